// Round 13
// baseline (181.193 us; speedup 1.0000x reference)
//
#include <hip/hip_runtime.h>
#include <cstdint>
#include <cstddef>

// AdMSoftmax loss, N=8192, D=256, S=1, M=0.4, unique-label branch.
//   G = x1 @ x2^T (fp8 MFMA, never materialized)
//   rownormsq_i = x1_i^T (X2^T X2) x1_i ; colnormsq_j = x2_j^T (X1^T X1) x2_j
//   rowExp_i = sum_j exp(G_ij/rn_i) ; colExp_j = sum_i exp(G_ij/cn_j) (fused epilogue)
//   L12_i = num - log(exp(num) + rowExp_i - exp(sim_ii)), num = sim_ii - 0.4
//   out = [loss, L12[8192], L21[8192]]
//
// R13: gemmE = R11 dbuf core with BK 64->128: 2 K-iters, 2 barrier drains
//      (R11 had 4; R12's zero-overlap single stage regressed 64->75us).
//      LDS 64KB -> 2 blocks/CU = unchanged (R11 was VGPR-capped at 2 anyway),
//      so barrier halving is free. Swizzle map identical (verified conflict-free,
//      SQ_LDS_BANK_CONFLICT=0 in R11). All other nodes R11-byte-identical.

#define NROWS 8192
#define DIMK 256
#define MARGIN 0.4f
#define LOG2E 1.4426950408889634f
#define LN2 0.6931471805599453f

typedef short short8 __attribute__((ext_vector_type(8)));
typedef float f32x4 __attribute__((ext_vector_type(4)));
typedef long longx2 __attribute__((ext_vector_type(2)));

__device__ __forceinline__ unsigned short f2bf(float f) {
  union { float f; unsigned u; } v; v.f = f;
  unsigned r = (v.u + 0x7fffu + ((v.u >> 16) & 1u)) >> 16;  // RNE
  return (unsigned short)r;
}

// fp32 -> OCP e4m3fn, RNE, saturate to 448
__device__ __forceinline__ unsigned char f2fp8(float f) {
  union { float f; unsigned u; } v; v.f = f;
  const unsigned s = (v.u >> 24) & 0x80u;
  const unsigned au = v.u & 0x7fffffffu;
  if (au >= 0x43e00000u) return (unsigned char)(s | 0x7eu);  // >=448 -> 448
  int e = (int)(au >> 23) - 127;
  if (e >= -6) {
    unsigned mfull = (au & 0x7fffffu) | 0x800000u;  // 24-bit 1.m
    unsigned r = (mfull + 0x7ffffu + ((mfull >> 20) & 1u)) >> 20;  // RNE to 4b (8..16)
    if (r == 16u) { r = 8u; ++e; }
    return (unsigned char)(s | ((unsigned)(e + 7) << 3) | (r & 7u));
  }
  float scaled = __builtin_fabsf(f) * 512.0f;  // subnormal: n * 2^-9
  unsigned n = (unsigned)(scaled + 0.5f);
  if (n >= 8u) return (unsigned char)(s | 0x08u);
  return (unsigned char)(s | n);
}

__device__ __forceinline__ void gl_lds16(const void* g, void* l) {
  __builtin_amdgcn_global_load_lds((const __attribute__((address_space(1))) void*)g,
                                   (__attribute__((address_space(3))) void*)l, 16, 0, 0);
}

__device__ __forceinline__ float fexp(float x) {
  return __builtin_amdgcn_exp2f(x * LOG2E);
}

// ---- node 1: convert x -> bf16 + fp8 + diag dot (blocks 0..2047) | zero
// accumulators (blocks 2048..2208). Race-free: consumers are later dispatches.
__global__ __launch_bounds__(256)
void k_prep(const float* __restrict__ x1, const float* __restrict__ x2,
            unsigned short* __restrict__ Ab, unsigned short* __restrict__ Bb,
            unsigned char* __restrict__ A8, unsigned char* __restrict__ B8,
            float* __restrict__ diag, float* __restrict__ zero_region) {
  const int t = threadIdx.x;
  if (blockIdx.x < 2048) {
    const int row = blockIdx.x * 4 + (t >> 6);
    const int l = t & 63;
    const float4 a = ((const float4*)(x1 + (size_t)row * DIMK))[l];
    const float4 b = ((const float4*)(x2 + (size_t)row * DIMK))[l];
    ushort4 ua, ub;
    ua.x = f2bf(a.x); ua.y = f2bf(a.y); ua.z = f2bf(a.z); ua.w = f2bf(a.w);
    ub.x = f2bf(b.x); ub.y = f2bf(b.y); ub.z = f2bf(b.z); ub.w = f2bf(b.w);
    ((ushort4*)(Ab + (size_t)row * DIMK))[l] = ua;
    ((ushort4*)(Bb + (size_t)row * DIMK))[l] = ub;
    uchar4 qa, qb;
    qa.x = f2fp8(a.x); qa.y = f2fp8(a.y); qa.z = f2fp8(a.z); qa.w = f2fp8(a.w);
    qb.x = f2fp8(b.x); qb.y = f2fp8(b.y); qb.z = f2fp8(b.z); qb.w = f2fp8(b.w);
    ((uchar4*)(A8 + (size_t)row * DIMK))[l] = qa;
    ((uchar4*)(B8 + (size_t)row * DIMK))[l] = qb;
    float d = a.x * b.x + a.y * b.y + a.z * b.z + a.w * b.w;
#pragma unroll
    for (int m = 1; m < 64; m <<= 1) d += __shfl_xor(d, m);
    if (l == 0) diag[row] = d;
  } else {
    const size_t off = (size_t)(blockIdx.x - 2048) * 1024 + t * 4;  // float units
    float4 z = {0.f, 0.f, 0.f, 0.f};
    *(float4*)(zero_region + off) = z;
  }
}

// ---- node 2: M = X^T X (256x256) via bf16 MFMA, 64x64 tiles, 16 K-segs, atomics ----
__global__ __launch_bounds__(256)
void k_syrk(const unsigned short* __restrict__ Ab, const unsigned short* __restrict__ Bb,
            float* __restrict__ M1, float* __restrict__ M2) {
  __shared__ unsigned short As[64 * 32];
  __shared__ unsigned short Bs[64 * 32];
  const int t = threadIdx.x, w = t >> 6, l = t & 63, quad = l >> 4, l15 = l & 15;
  const int mat = blockIdx.z & 1;
  const int kseg = blockIdx.z >> 1;
  const unsigned short* X = mat ? Bb : Ab;
  float* Mo = mat ? M2 : M1;
  const int a0 = blockIdx.y * 64, b0 = blockIdx.x * 64;
  const int wr = (w >> 1) * 32, wc = (w & 1) * 32;
  f32x4 acc[2][2] = {};
  const int nn = t & 31, cb = t >> 5;
  const int c0 = cb * 8;
  const int nb = kseg * 512;
  for (int n0 = nb; n0 < nb + 512; n0 += 32) {
    short8 va = *(const short8*)(X + (size_t)(n0 + nn) * DIMK + a0 + c0);
    short8 vb = *(const short8*)(X + (size_t)(n0 + nn) * DIMK + b0 + c0);
#pragma unroll
    for (int i = 0; i < 8; ++i) {
      const int c = c0 + i;
      const int sl = (((nn >> 3) ^ ((c >> 1) & 3)) << 3) + (nn & 7);
      As[c * 32 + sl] = va[i];
      Bs[c * 32 + sl] = vb[i];
    }
    __syncthreads();
    short8 af[2], bg[2];
#pragma unroll
    for (int i = 0; i < 2; ++i) {
      const int ra = wr + i * 16 + l15;
      af[i] = *(const short8*)&As[ra * 32 + ((quad ^ ((ra >> 1) & 3)) << 3)];
      const int rb = wc + i * 16 + l15;
      bg[i] = *(const short8*)&Bs[rb * 32 + ((quad ^ ((rb >> 1) & 3)) << 3)];
    }
#pragma unroll
    for (int i = 0; i < 2; ++i)
#pragma unroll
      for (int j = 0; j < 2; ++j)
        acc[i][j] = __builtin_amdgcn_mfma_f32_16x16x32_bf16(af[i], bg[j], acc[i][j], 0, 0, 0);
    __syncthreads();
  }
#pragma unroll
  for (int i = 0; i < 2; ++i)
#pragma unroll
    for (int j = 0; j < 2; ++j)
#pragma unroll
      for (int r = 0; r < 4; ++r) {
        const int lr = wr + i * 16 + quad * 4 + r;
        const int lc = wc + j * 16 + l15;
        atomicAdd(&Mo[(size_t)(a0 + lr) * 256 + b0 + lc], acc[i][j][r]);
      }
}

// ---- node 3: norm GEMM Y = X*M (M symmetric), fused dot epilogue -> rowsq/colsq.
// B staged from fp32 M with in-flight bf16 convert.
__global__ __launch_bounds__(256)
void k_gemmN(const unsigned short* __restrict__ Ab, const unsigned short* __restrict__ Bb,
             const float* __restrict__ M1, const float* __restrict__ M2,
             const float* __restrict__ x1, const float* __restrict__ x2,
             float* __restrict__ rowsq, float* __restrict__ colsq) {
  __shared__ unsigned short As[2][4096];
  __shared__ unsigned short Bs[2][4096];
  const int t = threadIdx.x, w = t >> 6, l = t & 63, quad = l >> 4, l15 = l & 15;
  const unsigned short* A;
  const float* Mf;
  const float* Xf;
  float* sq;
  if (blockIdx.z == 0) { A = Ab; Mf = M2; Xf = x1; sq = rowsq; }
  else                 { A = Bb; Mf = M1; Xf = x2; sq = colsq; }
  const int row0 = blockIdx.x * 128;
  const int col0 = blockIdx.y * 128;
  const int wr = (w >> 1) * 64, wc = (w & 1) * 64;
  f32x4 acc[4][4] = {};

  const int sr0 = l >> 2, slot = l & 3;
  const int cA = w * 2, cB = w * 2 + 1;
  const int rA = cA * 16 + sr0, rB = cB * 16 + sr0;
  const int scA = (slot ^ ((rA >> 1) & 3)) << 3;
  const int scB = (slot ^ ((rB >> 1) & 3)) << 3;
  const unsigned short* pA0 = A + (size_t)(row0 + rA) * DIMK + scA;
  const unsigned short* pA1 = A + (size_t)(row0 + rB) * DIMK + scB;
  const int dA0 = cA * 512 + l * 8, dA1 = cB * 512 + l * 8;

  auto stageB = [&](int k0, int buf) {
#pragma unroll
    for (int g = 0; g < 2; ++g) {
      const int e = g * 2048 + t * 8;
      const int c = e >> 5, kk = e & 31;
      const float4 v0 = *(const float4*)(Mf + (size_t)(col0 + c) * 256 + k0 + kk);
      const float4 v1 = *(const float4*)(Mf + (size_t)(col0 + c) * 256 + k0 + kk + 4);
      ushort4 u0, u1;
      u0.x = f2bf(v0.x); u0.y = f2bf(v0.y); u0.z = f2bf(v0.z); u0.w = f2bf(v0.w);
      u1.x = f2bf(v1.x); u1.y = f2bf(v1.y); u1.z = f2bf(v1.z); u1.w = f2bf(v1.w);
      const int sw = ((kk >> 3) ^ ((c >> 1) & 3)) << 3;
      *(ushort4*)&Bs[buf][c * 32 + sw] = u0;
      *(ushort4*)&Bs[buf][c * 32 + sw + 4] = u1;
    }
  };
  auto issueA = [&](int k0, int buf) {
    gl_lds16(pA0 + k0, &As[buf][dA0]);
    gl_lds16(pA1 + k0, &As[buf][dA1]);
  };

  stageB(0, 0);
  issueA(0, 0);
#pragma unroll
  for (int k = 0; k < 8; ++k) {
    const int cur = k & 1;
    __syncthreads();
    if (k < 7) { stageB((k + 1) * 32, cur ^ 1); issueA((k + 1) * 32, cur ^ 1); }
    short8 af[4], bg[4];
#pragma unroll
    for (int i = 0; i < 4; ++i) {
      const int ra = wr + i * 16 + l15;
      af[i] = *(const short8*)&As[cur][ra * 32 + ((quad ^ ((ra >> 1) & 3)) << 3)];
      const int rb = wc + i * 16 + l15;
      bg[i] = *(const short8*)&Bs[cur][rb * 32 + ((quad ^ ((rb >> 1) & 3)) << 3)];
    }
#pragma unroll
    for (int i = 0; i < 4; ++i)
#pragma unroll
      for (int j = 0; j < 4; ++j)
        acc[i][j] = __builtin_amdgcn_mfma_f32_16x16x32_bf16(af[i], bg[j], acc[i][j], 0, 0, 0);
  }

#pragma unroll
  for (int i = 0; i < 4; ++i) {
#pragma unroll
    for (int r = 0; r < 4; ++r) {
      const int lr = wr + i * 16 + quad * 4 + r;
      const float* xr = Xf + (size_t)(row0 + lr) * DIMK + col0 + wc;
      float rp = 0.f;
#pragma unroll
      for (int j = 0; j < 4; ++j) rp += acc[i][j][r] * xr[j * 16 + l15];
      rp += __shfl_xor(rp, 1); rp += __shfl_xor(rp, 2);
      rp += __shfl_xor(rp, 4); rp += __shfl_xor(rp, 8);
      if (l15 == 0) atomicAdd(&sq[row0 + lr], rp);
    }
  }
}

// ---- node 4: main GEMM + exp epilogue. fp8, BK=128 dbuf, 2 barriers. ----
// Per-64B-K-chunk layout = R11's verified conflict-free map: row(128) x 4 phys
// 16B chunks, pc = quad ^ ((row>>1)&3), staging un-swizzles on the global
// address (LDS dst stays wave-uniform + lane*16). One ds_read_b128 feeds two
// MFMAs via the virtual-k repartition (identical for A and B -> exact).
__global__ __launch_bounds__(256)
void k_gemmE(const unsigned char* __restrict__ A8, const unsigned char* __restrict__ B8,
             const float* __restrict__ rowsq, const float* __restrict__ colsq,
             float* __restrict__ rowExp, float* __restrict__ colExp) {
  __shared__ unsigned char As[2][16384];  // [sub(2)][8192 = 128 rows x 64B]
  __shared__ unsigned char Bs[2][16384];
  __shared__ float cRow[128];
  __shared__ float cCol[128];

  const int t = threadIdx.x;
  const int w = t >> 6;
  const int l = t & 63;
  const int quad = l >> 4;
  const int l15 = l & 15;
  const int row0 = blockIdx.x * 128;
  const int col0 = blockIdx.y * 128;
  const int wr = (w >> 1) * 64;
  const int wc = (w & 1) * 64;

  if (t < 128) cRow[t] = LOG2E * rsqrtf(rowsq[row0 + t]);
  else cCol[t - 128] = LOG2E * rsqrtf(colsq[col0 + t - 128]);

  f32x4 acc[4][4] = {};

  // staging: physical slot p=t -> (row=t>>2, pc=t&3), p=t+256 -> (row=64+(t>>2), pc).
  // required logical chunk cl = pc ^ ((row>>1)&3) = (t&3) ^ ((t>>3)&3) for both.
  const int srow = t >> 2;
  const int cl = (t & 3) ^ ((t >> 3) & 3);
  const unsigned char* gA0 = A8 + (size_t)(row0 + srow) * DIMK + cl * 16;
  const unsigned char* gA1 = A8 + (size_t)(row0 + 64 + srow) * DIMK + cl * 16;
  const unsigned char* gB0 = B8 + (size_t)(col0 + srow) * DIMK + cl * 16;
  const unsigned char* gB1 = B8 + (size_t)(col0 + 64 + srow) * DIMK + cl * 16;
  const int d0 = t * 16, d1 = 4096 + t * 16;

  auto issue = [&](int k0, int buf) {  // stage 128 K-cols = 2 sub-chunks of 64
#pragma unroll
    for (int sub = 0; sub < 2; ++sub) {
      gl_lds16(gA0 + k0 + sub * 64, &As[buf][sub * 8192 + d0]);
      gl_lds16(gA1 + k0 + sub * 64, &As[buf][sub * 8192 + d1]);
      gl_lds16(gB0 + k0 + sub * 64, &Bs[buf][sub * 8192 + d0]);
      gl_lds16(gB1 + k0 + sub * 64, &Bs[buf][sub * 8192 + d1]);
    }
  };

  issue(0, 0);
#pragma unroll
  for (int it = 0; it < 2; ++it) {
    const int cur = it & 1;
    __syncthreads();
    if (it < 1) issue(128, 1);
#pragma unroll
    for (int sub = 0; sub < 2; ++sub) {
      longx2 av[4], bv[4];
#pragma unroll
      for (int i = 0; i < 4; ++i) {
        const int ra = wr + i * 16 + l15;
        const int pcA = quad ^ ((ra >> 1) & 3);
        av[i] = *(const longx2*)&As[cur][sub * 8192 + ra * 64 + pcA * 16];
        const int rb = wc + i * 16 + l15;
        const int pcB = quad ^ ((rb >> 1) & 3);
        bv[i] = *(const longx2*)&Bs[cur][sub * 8192 + rb * 64 + pcB * 16];
      }
#pragma unroll
      for (int kk = 0; kk < 2; ++kk)
#pragma unroll
        for (int i = 0; i < 4; ++i)
#pragma unroll
          for (int j = 0; j < 4; ++j)
            acc[i][j] = __builtin_amdgcn_mfma_f32_16x16x32_fp8_fp8(av[i][kk], bv[j][kk],
                                                                   acc[i][j], 0, 0, 0);
    }
  }

  // exp epilogue. C/D layout: row_local = wr+i*16+quad*4+r ; col_local = wc+j*16+l15
  float cj[4];
#pragma unroll
  for (int j = 0; j < 4; ++j) cj[j] = cCol[wc + j * 16 + l15];
  float colpart[4] = {0.f, 0.f, 0.f, 0.f};
#pragma unroll
  for (int i = 0; i < 4; ++i) {
#pragma unroll
    for (int r = 0; r < 4; ++r) {
      const int lr = wr + i * 16 + quad * 4 + r;
      const float ci = cRow[lr];
      float rp = 0.f;
#pragma unroll
      for (int j = 0; j < 4; ++j) {
        const float g = acc[i][j][r];
        rp += __builtin_amdgcn_exp2f(g * ci);
        colpart[j] += __builtin_amdgcn_exp2f(g * cj[j]);
      }
      rp += __shfl_xor(rp, 1); rp += __shfl_xor(rp, 2);
      rp += __shfl_xor(rp, 4); rp += __shfl_xor(rp, 8);
      if (l15 == 0) atomicAdd(&rowExp[row0 + lr], rp);
    }
  }
#pragma unroll
  for (int j = 0; j < 4; ++j) {
    float cp = colpart[j];
    cp += __shfl_xor(cp, 16); cp += __shfl_xor(cp, 32);
    if (l < 16) atomicAdd(&colExp[col0 + wc + j * 16 + l15], cp);
  }
}

// ---- node 5: finalize, 8 blocks x 1024 thr; fp64 atomic loss + last-arrival out[0] ----
__global__ __launch_bounds__(1024)
void k_final(const float* __restrict__ rowsq, const float* __restrict__ colsq,
             const float* __restrict__ diag, const float* __restrict__ rowExp,
             const float* __restrict__ colExp, float* __restrict__ out,
             double* __restrict__ lossAcc, int* __restrict__ doneCnt) {
  const int t = threadIdx.x;
  const int i = blockIdx.x * 1024 + t;
  const float d = diag[i];
  const float s1 = d * rsqrtf(rowsq[i]);
  const float s2 = d * rsqrtf(colsq[i]);
  const float n1 = s1 - MARGIN, n2 = s2 - MARGIN;
  const float L1 = n1 - LN2 * __builtin_amdgcn_logf(rowExp[i] - fexp(s1) + fexp(n1));
  const float L2 = n2 - LN2 * __builtin_amdgcn_logf(colExp[i] - fexp(s2) + fexp(n2));
  out[1 + i] = L1;
  out[1 + NROWS + i] = L2;
  double part = (double)L1 + (double)L2;
#pragma unroll
  for (int m = 1; m < 64; m <<= 1) part += __shfl_xor(part, m);
  __shared__ double red[16];
  if ((t & 63) == 0) red[t >> 6] = part;
  __syncthreads();
  if (t == 0) {
    double s = 0.0;
#pragma unroll
    for (int q = 0; q < 16; ++q) s += red[q];
    atomicAdd(lossAcc, s);
    __threadfence();  // only 8 blocks pay this
    if (atomicAdd(doneCnt, 1) == 7) {
      const double la =
          __hip_atomic_load(lossAcc, __ATOMIC_ACQUIRE, __HIP_MEMORY_SCOPE_AGENT);
      out[0] = (float)(-la / (double)NROWS);
    }
  }
}

extern "C" void kernel_launch(void* const* d_in, const int* in_sizes, int n_in,
                              void* d_out, int out_size, void* d_ws, size_t ws_size,
                              hipStream_t stream) {
  const float* x1 = (const float*)d_in[0];
  const float* x2 = (const float*)d_in[1];
  float* out = (float*)d_out;
  char* ws = (char*)d_ws;

  unsigned short* Ab = (unsigned short*)(ws);            // 4 MB  x1 bf16
  unsigned short* Bb = (unsigned short*)(ws + 4194304);  // 4 MB  x2 bf16
  // zero region: 8388608 .. +659456 (161 blocks x 4096 B) covers M1..ctrl
  float* M1 = (float*)(ws + 8388608);      // 256 KB  X1^T X1 (fp32 acc)
  float* M2 = (float*)(ws + 8650752);      // 256 KB  X2^T X2
  float* rowsq = (float*)(ws + 8912896);   // 32 KB
  float* colsq = (float*)(ws + 8945664);   // 32 KB
  float* rowExp = (float*)(ws + 8978432);  // 32 KB
  float* colExp = (float*)(ws + 9011200);  // 32 KB
  char* ctrl = ws + 9043968;               // 4 KB control page (zeroed)
  double* lossAcc = (double*)(ctrl);
  int* doneCnt = (int*)(ctrl + 256);
  float* diag = (float*)(ws + 9048064);    // 32 KB (not zeroed)
  unsigned char* A8 = (unsigned char*)(ws + 9080832);   // 2 MB  x1 fp8
  unsigned char* B8 = (unsigned char*)(ws + 11177984);  // 2 MB  x2 fp8

  k_prep<<<2209, 256, 0, stream>>>(x1, x2, Ab, Bb, A8, B8, diag,
                                   (float*)(ws + 8388608));
  k_syrk<<<dim3(4, 4, 32), 256, 0, stream>>>(Ab, Bb, M1, M2);
  k_gemmN<<<dim3(64, 2, 2), 256, 0, stream>>>(Ab, Bb, M1, M2, x1, x2, rowsq, colsq);
  k_gemmE<<<dim3(64, 64), 256, 0, stream>>>(A8, B8, rowsq, colsq, rowExp, colExp);
  k_final<<<8, 1024, 0, stream>>>(rowsq, colsq, diag, rowExp, colExp, out,
                                  lossAcc, doneCnt);
}

// Round 14
// 170.865 us; speedup vs baseline: 1.0604x; 1.0604x over previous
//
#include <hip/hip_runtime.h>
#include <cstdint>
#include <cstddef>

// AdMSoftmax loss, N=8192, D=256, S=1, M=0.4, unique-label branch.
//   G = x1 @ x2^T (fp8 MFMA, never materialized)
//   rownormsq_i = x1_i^T (X2^T X2) x1_i ; colnormsq_j = x2_j^T (X1^T X1) x2_j
//   rowExp_i = sum_j exp(G_ij/rn_i) ; colExp_j = sum_i exp(G_ij/cn_j) (fused epilogue)
//   L12_i = num - log(exp(num) + rowExp_i - exp(sim_ii)), num = sim_ii - 0.4
//   out = [loss, L12[8192], L21[8192]]
//
// R14: gemmE = R11-verbatim (64us; R12 single-stage and R13 BK=128 both lost —
//      BK=64/4-barrier/33.8KB is the verified optimum of this shape). Residual
//      attack: small kernels are serial-depth-bound -> syrk K-segs 16->32
//      (8 iters/block, 1024 blocks), gemmN K-split x2 (4 iters/block, 512
//      blocks; dot epilogue linear in C -> atomic partials exact).

#define NROWS 8192
#define DIMK 256
#define MARGIN 0.4f
#define LOG2E 1.4426950408889634f
#define LN2 0.6931471805599453f

typedef short short8 __attribute__((ext_vector_type(8)));
typedef float f32x4 __attribute__((ext_vector_type(4)));
typedef long longx2 __attribute__((ext_vector_type(2)));

__device__ __forceinline__ unsigned short f2bf(float f) {
  union { float f; unsigned u; } v; v.f = f;
  unsigned r = (v.u + 0x7fffu + ((v.u >> 16) & 1u)) >> 16;  // RNE
  return (unsigned short)r;
}

// fp32 -> OCP e4m3fn, RNE, saturate to 448
__device__ __forceinline__ unsigned char f2fp8(float f) {
  union { float f; unsigned u; } v; v.f = f;
  const unsigned s = (v.u >> 24) & 0x80u;
  const unsigned au = v.u & 0x7fffffffu;
  if (au >= 0x43e00000u) return (unsigned char)(s | 0x7eu);  // >=448 -> 448
  int e = (int)(au >> 23) - 127;
  if (e >= -6) {
    unsigned mfull = (au & 0x7fffffu) | 0x800000u;  // 24-bit 1.m
    unsigned r = (mfull + 0x7ffffu + ((mfull >> 20) & 1u)) >> 20;  // RNE to 4b (8..16)
    if (r == 16u) { r = 8u; ++e; }
    return (unsigned char)(s | ((unsigned)(e + 7) << 3) | (r & 7u));
  }
  float scaled = __builtin_fabsf(f) * 512.0f;  // subnormal: n * 2^-9
  unsigned n = (unsigned)(scaled + 0.5f);
  if (n >= 8u) return (unsigned char)(s | 0x08u);
  return (unsigned char)(s | n);
}

__device__ __forceinline__ void gl_lds16(const void* g, void* l) {
  __builtin_amdgcn_global_load_lds((const __attribute__((address_space(1))) void*)g,
                                   (__attribute__((address_space(3))) void*)l, 16, 0, 0);
}

__device__ __forceinline__ float fexp(float x) {
  return __builtin_amdgcn_exp2f(x * LOG2E);
}

// ---- node 1: convert x -> bf16 + fp8 + diag dot (blocks 0..2047) | zero
// accumulators (blocks 2048..2208). Race-free: consumers are later dispatches.
__global__ __launch_bounds__(256)
void k_prep(const float* __restrict__ x1, const float* __restrict__ x2,
            unsigned short* __restrict__ Ab, unsigned short* __restrict__ Bb,
            unsigned char* __restrict__ A8, unsigned char* __restrict__ B8,
            float* __restrict__ diag, float* __restrict__ zero_region) {
  const int t = threadIdx.x;
  if (blockIdx.x < 2048) {
    const int row = blockIdx.x * 4 + (t >> 6);
    const int l = t & 63;
    const float4 a = ((const float4*)(x1 + (size_t)row * DIMK))[l];
    const float4 b = ((const float4*)(x2 + (size_t)row * DIMK))[l];
    ushort4 ua, ub;
    ua.x = f2bf(a.x); ua.y = f2bf(a.y); ua.z = f2bf(a.z); ua.w = f2bf(a.w);
    ub.x = f2bf(b.x); ub.y = f2bf(b.y); ub.z = f2bf(b.z); ub.w = f2bf(b.w);
    ((ushort4*)(Ab + (size_t)row * DIMK))[l] = ua;
    ((ushort4*)(Bb + (size_t)row * DIMK))[l] = ub;
    uchar4 qa, qb;
    qa.x = f2fp8(a.x); qa.y = f2fp8(a.y); qa.z = f2fp8(a.z); qa.w = f2fp8(a.w);
    qb.x = f2fp8(b.x); qb.y = f2fp8(b.y); qb.z = f2fp8(b.z); qb.w = f2fp8(b.w);
    ((uchar4*)(A8 + (size_t)row * DIMK))[l] = qa;
    ((uchar4*)(B8 + (size_t)row * DIMK))[l] = qb;
    float d = a.x * b.x + a.y * b.y + a.z * b.z + a.w * b.w;
#pragma unroll
    for (int m = 1; m < 64; m <<= 1) d += __shfl_xor(d, m);
    if (l == 0) diag[row] = d;
  } else {
    const size_t off = (size_t)(blockIdx.x - 2048) * 1024 + t * 4;  // float units
    float4 z = {0.f, 0.f, 0.f, 0.f};
    *(float4*)(zero_region + off) = z;
  }
}

// ---- node 2: M = X^T X (256x256) via bf16 MFMA, 64x64 tiles, 32 K-segs of 256,
// 8 iters/block (serial depth halved vs R11), fp32 atomic accumulate ----
__global__ __launch_bounds__(256)
void k_syrk(const unsigned short* __restrict__ Ab, const unsigned short* __restrict__ Bb,
            float* __restrict__ M1, float* __restrict__ M2) {
  __shared__ unsigned short As[64 * 32];
  __shared__ unsigned short Bs[64 * 32];
  const int t = threadIdx.x, w = t >> 6, l = t & 63, quad = l >> 4, l15 = l & 15;
  const int mat = blockIdx.z & 1;
  const int kseg = blockIdx.z >> 1;  // 0..31, 256 rows each
  const unsigned short* X = mat ? Bb : Ab;
  float* Mo = mat ? M2 : M1;
  const int a0 = blockIdx.y * 64, b0 = blockIdx.x * 64;
  const int wr = (w >> 1) * 32, wc = (w & 1) * 32;
  f32x4 acc[2][2] = {};
  const int nn = t & 31, cb = t >> 5;
  const int c0 = cb * 8;
  const int nb = kseg * 256;
  for (int n0 = nb; n0 < nb + 256; n0 += 32) {
    short8 va = *(const short8*)(X + (size_t)(n0 + nn) * DIMK + a0 + c0);
    short8 vb = *(const short8*)(X + (size_t)(n0 + nn) * DIMK + b0 + c0);
#pragma unroll
    for (int i = 0; i < 8; ++i) {
      const int c = c0 + i;
      const int sl = (((nn >> 3) ^ ((c >> 1) & 3)) << 3) + (nn & 7);
      As[c * 32 + sl] = va[i];
      Bs[c * 32 + sl] = vb[i];
    }
    __syncthreads();
    short8 af[2], bg[2];
#pragma unroll
    for (int i = 0; i < 2; ++i) {
      const int ra = wr + i * 16 + l15;
      af[i] = *(const short8*)&As[ra * 32 + ((quad ^ ((ra >> 1) & 3)) << 3)];
      const int rb = wc + i * 16 + l15;
      bg[i] = *(const short8*)&Bs[rb * 32 + ((quad ^ ((rb >> 1) & 3)) << 3)];
    }
#pragma unroll
    for (int i = 0; i < 2; ++i)
#pragma unroll
      for (int j = 0; j < 2; ++j)
        acc[i][j] = __builtin_amdgcn_mfma_f32_16x16x32_bf16(af[i], bg[j], acc[i][j], 0, 0, 0);
    __syncthreads();
  }
#pragma unroll
  for (int i = 0; i < 2; ++i)
#pragma unroll
    for (int j = 0; j < 2; ++j)
#pragma unroll
      for (int r = 0; r < 4; ++r) {
        const int lr = wr + i * 16 + quad * 4 + r;
        const int lc = wc + j * 16 + l15;
        atomicAdd(&Mo[(size_t)(a0 + lr) * 256 + b0 + lc], acc[i][j][r]);
      }
}

// ---- node 3: norm GEMM Y = X*M (M symmetric), fused dot epilogue -> rowsq/colsq.
// B staged from fp32 M with in-flight bf16 convert. K-split x2 via grid.z>>1
// (partial-C dot is linear; atomicAdd accumulates exactly). 4 iters/block.
__global__ __launch_bounds__(256)
void k_gemmN(const unsigned short* __restrict__ Ab, const unsigned short* __restrict__ Bb,
             const float* __restrict__ M1, const float* __restrict__ M2,
             const float* __restrict__ x1, const float* __restrict__ x2,
             float* __restrict__ rowsq, float* __restrict__ colsq) {
  __shared__ unsigned short As[2][4096];
  __shared__ unsigned short Bs[2][4096];
  const int t = threadIdx.x, w = t >> 6, l = t & 63, quad = l >> 4, l15 = l & 15;
  const unsigned short* A;
  const float* Mf;
  const float* Xf;
  float* sq;
  if ((blockIdx.z & 1) == 0) { A = Ab; Mf = M2; Xf = x1; sq = rowsq; }
  else                       { A = Bb; Mf = M1; Xf = x2; sq = colsq; }
  const int kbase = (blockIdx.z >> 1) * 128;  // K-split segment
  const int row0 = blockIdx.x * 128;
  const int col0 = blockIdx.y * 128;
  const int wr = (w >> 1) * 64, wc = (w & 1) * 64;
  f32x4 acc[4][4] = {};

  const int sr0 = l >> 2, slot = l & 3;
  const int cA = w * 2, cB = w * 2 + 1;
  const int rA = cA * 16 + sr0, rB = cB * 16 + sr0;
  const int scA = (slot ^ ((rA >> 1) & 3)) << 3;
  const int scB = (slot ^ ((rB >> 1) & 3)) << 3;
  const unsigned short* pA0 = A + (size_t)(row0 + rA) * DIMK + kbase + scA;
  const unsigned short* pA1 = A + (size_t)(row0 + rB) * DIMK + kbase + scB;
  const int dA0 = cA * 512 + l * 8, dA1 = cB * 512 + l * 8;

  auto stageB = [&](int k0, int buf) {
#pragma unroll
    for (int g = 0; g < 2; ++g) {
      const int e = g * 2048 + t * 8;
      const int c = e >> 5, kk = e & 31;
      const float4 v0 = *(const float4*)(Mf + (size_t)(col0 + c) * 256 + kbase + k0 + kk);
      const float4 v1 = *(const float4*)(Mf + (size_t)(col0 + c) * 256 + kbase + k0 + kk + 4);
      ushort4 u0, u1;
      u0.x = f2bf(v0.x); u0.y = f2bf(v0.y); u0.z = f2bf(v0.z); u0.w = f2bf(v0.w);
      u1.x = f2bf(v1.x); u1.y = f2bf(v1.y); u1.z = f2bf(v1.z); u1.w = f2bf(v1.w);
      const int sw = ((kk >> 3) ^ ((c >> 1) & 3)) << 3;
      *(ushort4*)&Bs[buf][c * 32 + sw] = u0;
      *(ushort4*)&Bs[buf][c * 32 + sw + 4] = u1;
    }
  };
  auto issueA = [&](int k0, int buf) {
    gl_lds16(pA0 + k0, &As[buf][dA0]);
    gl_lds16(pA1 + k0, &As[buf][dA1]);
  };

  stageB(0, 0);
  issueA(0, 0);
#pragma unroll
  for (int k = 0; k < 4; ++k) {
    const int cur = k & 1;
    __syncthreads();
    if (k < 3) { stageB((k + 1) * 32, cur ^ 1); issueA((k + 1) * 32, cur ^ 1); }
    short8 af[4], bg[4];
#pragma unroll
    for (int i = 0; i < 4; ++i) {
      const int ra = wr + i * 16 + l15;
      af[i] = *(const short8*)&As[cur][ra * 32 + ((quad ^ ((ra >> 1) & 3)) << 3)];
      const int rb = wc + i * 16 + l15;
      bg[i] = *(const short8*)&Bs[cur][rb * 32 + ((quad ^ ((rb >> 1) & 3)) << 3)];
    }
#pragma unroll
    for (int i = 0; i < 4; ++i)
#pragma unroll
      for (int j = 0; j < 4; ++j)
        acc[i][j] = __builtin_amdgcn_mfma_f32_16x16x32_bf16(af[i], bg[j], acc[i][j], 0, 0, 0);
  }

#pragma unroll
  for (int i = 0; i < 4; ++i) {
#pragma unroll
    for (int r = 0; r < 4; ++r) {
      const int lr = wr + i * 16 + quad * 4 + r;
      const float* xr = Xf + (size_t)(row0 + lr) * DIMK + col0 + wc;
      float rp = 0.f;
#pragma unroll
      for (int j = 0; j < 4; ++j) rp += acc[i][j][r] * xr[j * 16 + l15];
      rp += __shfl_xor(rp, 1); rp += __shfl_xor(rp, 2);
      rp += __shfl_xor(rp, 4); rp += __shfl_xor(rp, 8);
      if (l15 == 0) atomicAdd(&sq[row0 + lr], rp);
    }
  }
}

// ---- node 4: main GEMM + exp epilogue (R11-verbatim: fp8, BK=64, dbuf,
// conflict-free b128 fragment swizzle; SQ_LDS_BANK_CONFLICT=0 measured). ----
__global__ __launch_bounds__(256)
void k_gemmE(const unsigned char* __restrict__ A8, const unsigned char* __restrict__ B8,
             const float* __restrict__ rowsq, const float* __restrict__ colsq,
             float* __restrict__ rowExp, float* __restrict__ colExp) {
  __shared__ unsigned char As[2][8192];
  __shared__ unsigned char Bs[2][8192];
  __shared__ float cRow[128];
  __shared__ float cCol[128];

  const int t = threadIdx.x;
  const int w = t >> 6;
  const int l = t & 63;
  const int quad = l >> 4;
  const int l15 = l & 15;
  const int row0 = blockIdx.x * 128;
  const int col0 = blockIdx.y * 128;
  const int wr = (w >> 1) * 64;
  const int wc = (w & 1) * 64;

  if (t < 128) cRow[t] = LOG2E * rsqrtf(rowsq[row0 + t]);
  else cCol[t - 128] = LOG2E * rsqrtf(colsq[col0 + t - 128]);

  f32x4 acc[4][4] = {};

  // staging: physical slot p=t -> (row=t>>2, pc=t&3), p=t+256 -> (row=64+(t>>2), pc).
  // required logical chunk cl = pc ^ ((row>>1)&3) = (t&3) ^ ((t>>3)&3) for both.
  const int srow = t >> 2;
  const int cl = (t & 3) ^ ((t >> 3) & 3);
  const unsigned char* gA0 = A8 + (size_t)(row0 + srow) * DIMK + cl * 16;
  const unsigned char* gA1 = A8 + (size_t)(row0 + 64 + srow) * DIMK + cl * 16;
  const unsigned char* gB0 = B8 + (size_t)(col0 + srow) * DIMK + cl * 16;
  const unsigned char* gB1 = B8 + (size_t)(col0 + 64 + srow) * DIMK + cl * 16;
  const int d0 = t * 16, d1 = 4096 + t * 16;

  auto issue = [&](int k0, int buf) {
    gl_lds16(gA0 + k0, &As[buf][d0]);
    gl_lds16(gA1 + k0, &As[buf][d1]);
    gl_lds16(gB0 + k0, &Bs[buf][d0]);
    gl_lds16(gB1 + k0, &Bs[buf][d1]);
  };

  issue(0, 0);
#pragma unroll
  for (int it = 0; it < 4; ++it) {
    const int cur = it & 1;
    __syncthreads();
    if (it < 3) issue((it + 1) * 64, cur ^ 1);
    longx2 av[4], bv[4];
#pragma unroll
    for (int i = 0; i < 4; ++i) {
      const int ra = wr + i * 16 + l15;
      const int pcA = quad ^ ((ra >> 1) & 3);
      av[i] = *(const longx2*)&As[cur][ra * 64 + pcA * 16];
      const int rb = wc + i * 16 + l15;
      const int pcB = quad ^ ((rb >> 1) & 3);
      bv[i] = *(const longx2*)&Bs[cur][rb * 64 + pcB * 16];
    }
#pragma unroll
    for (int kc = 0; kc < 2; ++kc)
#pragma unroll
      for (int i = 0; i < 4; ++i)
#pragma unroll
        for (int j = 0; j < 4; ++j)
          acc[i][j] = __builtin_amdgcn_mfma_f32_16x16x32_fp8_fp8(av[i][kc], bv[j][kc],
                                                                 acc[i][j], 0, 0, 0);
  }

  // exp epilogue. C/D layout: row_local = wr+i*16+quad*4+r ; col_local = wc+j*16+l15
  float cj[4];
#pragma unroll
  for (int j = 0; j < 4; ++j) cj[j] = cCol[wc + j * 16 + l15];
  float colpart[4] = {0.f, 0.f, 0.f, 0.f};
#pragma unroll
  for (int i = 0; i < 4; ++i) {
#pragma unroll
    for (int r = 0; r < 4; ++r) {
      const int lr = wr + i * 16 + quad * 4 + r;
      const float ci = cRow[lr];
      float rp = 0.f;
#pragma unroll
      for (int j = 0; j < 4; ++j) {
        const float g = acc[i][j][r];
        rp += __builtin_amdgcn_exp2f(g * ci);
        colpart[j] += __builtin_amdgcn_exp2f(g * cj[j]);
      }
      rp += __shfl_xor(rp, 1); rp += __shfl_xor(rp, 2);
      rp += __shfl_xor(rp, 4); rp += __shfl_xor(rp, 8);
      if (l15 == 0) atomicAdd(&rowExp[row0 + lr], rp);
    }
  }
#pragma unroll
  for (int j = 0; j < 4; ++j) {
    float cp = colpart[j];
    cp += __shfl_xor(cp, 16); cp += __shfl_xor(cp, 32);
    if (l < 16) atomicAdd(&colExp[col0 + wc + j * 16 + l15], cp);
  }
}

// ---- node 5: finalize, 8 blocks x 1024 thr; fp64 atomic loss + last-arrival out[0] ----
__global__ __launch_bounds__(1024)
void k_final(const float* __restrict__ rowsq, const float* __restrict__ colsq,
             const float* __restrict__ diag, const float* __restrict__ rowExp,
             const float* __restrict__ colExp, float* __restrict__ out,
             double* __restrict__ lossAcc, int* __restrict__ doneCnt) {
  const int t = threadIdx.x;
  const int i = blockIdx.x * 1024 + t;
  const float d = diag[i];
  const float s1 = d * rsqrtf(rowsq[i]);
  const float s2 = d * rsqrtf(colsq[i]);
  const float n1 = s1 - MARGIN, n2 = s2 - MARGIN;
  const float L1 = n1 - LN2 * __builtin_amdgcn_logf(rowExp[i] - fexp(s1) + fexp(n1));
  const float L2 = n2 - LN2 * __builtin_amdgcn_logf(colExp[i] - fexp(s2) + fexp(n2));
  out[1 + i] = L1;
  out[1 + NROWS + i] = L2;
  double part = (double)L1 + (double)L2;
#pragma unroll
  for (int m = 1; m < 64; m <<= 1) part += __shfl_xor(part, m);
  __shared__ double red[16];
  if ((t & 63) == 0) red[t >> 6] = part;
  __syncthreads();
  if (t == 0) {
    double s = 0.0;
#pragma unroll
    for (int q = 0; q < 16; ++q) s += red[q];
    atomicAdd(lossAcc, s);
    __threadfence();  // only 8 blocks pay this
    if (atomicAdd(doneCnt, 1) == 7) {
      const double la =
          __hip_atomic_load(lossAcc, __ATOMIC_ACQUIRE, __HIP_MEMORY_SCOPE_AGENT);
      out[0] = (float)(-la / (double)NROWS);
    }
  }
}

extern "C" void kernel_launch(void* const* d_in, const int* in_sizes, int n_in,
                              void* d_out, int out_size, void* d_ws, size_t ws_size,
                              hipStream_t stream) {
  const float* x1 = (const float*)d_in[0];
  const float* x2 = (const float*)d_in[1];
  float* out = (float*)d_out;
  char* ws = (char*)d_ws;

  unsigned short* Ab = (unsigned short*)(ws);            // 4 MB  x1 bf16
  unsigned short* Bb = (unsigned short*)(ws + 4194304);  // 4 MB  x2 bf16
  // zero region: 8388608 .. +659456 (161 blocks x 4096 B) covers M1..ctrl
  float* M1 = (float*)(ws + 8388608);      // 256 KB  X1^T X1 (fp32 acc)
  float* M2 = (float*)(ws + 8650752);      // 256 KB  X2^T X2
  float* rowsq = (float*)(ws + 8912896);   // 32 KB
  float* colsq = (float*)(ws + 8945664);   // 32 KB
  float* rowExp = (float*)(ws + 8978432);  // 32 KB
  float* colExp = (float*)(ws + 9011200);  // 32 KB
  char* ctrl = ws + 9043968;               // 4 KB control page (zeroed)
  double* lossAcc = (double*)(ctrl);
  int* doneCnt = (int*)(ctrl + 256);
  float* diag = (float*)(ws + 9048064);    // 32 KB (not zeroed)
  unsigned char* A8 = (unsigned char*)(ws + 9080832);   // 2 MB  x1 fp8
  unsigned char* B8 = (unsigned char*)(ws + 11177984);  // 2 MB  x2 fp8

  k_prep<<<2209, 256, 0, stream>>>(x1, x2, Ab, Bb, A8, B8, diag,
                                   (float*)(ws + 8388608));
  k_syrk<<<dim3(4, 4, 64), 256, 0, stream>>>(Ab, Bb, M1, M2);
  k_gemmN<<<dim3(64, 2, 4), 256, 0, stream>>>(Ab, Bb, M1, M2, x1, x2, rowsq, colsq);
  k_gemmE<<<dim3(64, 64), 256, 0, stream>>>(A8, B8, rowsq, colsq, rowExp, colExp);
  k_final<<<8, 1024, 0, stream>>>(rowsq, colsq, diag, rowExp, colExp, out,
                                  lossAcc, doneCnt);
}